// Round 24
// 224.860 us; speedup vs baseline: 2.1120x; 1.0317x over previous
//
#include <hip/hip_runtime.h>
#include <hip/hip_bf16.h>

typedef __hip_bfloat16 bf16;
typedef __attribute__((ext_vector_type(8))) short short8v;
typedef __attribute__((ext_vector_type(4))) float f32x4;

#define NN 4096
#define NE 32768
#define HH 128
#define MAXZ 100
#define TPB 8
#define NB 1

// ENVIRONMENT FACTS (r0-r23): float tensors are FLOAT32; runtime detector kept.
// MFMA edge path validated r10/r16/r19/r21/r22; MFMA cmix validated r17/r18;
// fusions r20; merged-layer+LDS-staged edge r22/r23 (232.0us, absmax
// 0.002929688). ws_size ~256MB. r24: edge kernel is VALU-issue-bound
// (VALUBusy 57%, MfmaUtil 12.5%); siluf's f32 divide compiles to the ~10-inst
// IEEE sequence without fast-math. Replace divides in siluf / cmix_norm inv /
// sab inv with v_rcp_f32 (~1 ulp; absorbed by bf16 rounding downstream).
// absmax may drift slightly; must stay << 6.29e-3.

__device__ __forceinline__ float b2f(bf16 v){ return __bfloat162float(v); }
__device__ __forceinline__ float ldf(const float* p, size_t i){ return p[i]; }
__device__ __forceinline__ float ldf(const bf16*  p, size_t i){ return __bfloat162float(p[i]); }
__device__ __forceinline__ float siluf(float x){ return x * __builtin_amdgcn_rcpf(1.0f + __expf(-x)); }
__device__ __forceinline__ unsigned short f2bu(float x){
  bf16 h = __float2bfloat16(x);
  return *reinterpret_cast<unsigned short*>(&h);
}
__device__ __forceinline__ float bround(float x){   // round through bf16 (matches old smb round-trip)
  bf16 h = __float2bfloat16(x);
  return __bfloat162float(h);
}

__global__ void __launch_bounds__(256) k_detect(const unsigned int* __restrict__ w, int* __restrict__ flag){
  __shared__ int cnt[256];
  int t = threadIdx.x;
  int c = 0;
  for (int i = t; i < 4096; i += 256){
    unsigned int lo = w[i] & 0xffffu;
    int e = (int)((lo >> 7) & 0xffu);
    c += (e >= 110 && e <= 132) ? 1 : 0;
  }
  cnt[t] = c; __syncthreads();
  for (int off=128; off>=1; off>>=1){ if (t<off) cnt[t]+=cnt[t+off]; __syncthreads(); }
  if (t==0) flag[0] = (cnt[0] < 2048) ? 1 : 0;
}

// ---------------- CSR build ----------------
__global__ void __launch_bounds__(256) k_count(const int* __restrict__ dst, int* __restrict__ counts){
  int e = blockIdx.x*256 + threadIdx.x;
  if (e < NE) atomicAdd(&counts[dst[e]], 1);
}

__global__ void __launch_bounds__(1024) k_scan(const int* __restrict__ counts, int* __restrict__ offsets, int* __restrict__ cursor){
  __shared__ int lds[1024];
  int t = threadIdx.x;
  int c0 = counts[4*t+0], c1 = counts[4*t+1], c2 = counts[4*t+2], c3 = counts[4*t+3];
  int s1 = c0+c1, s2 = s1+c2, s3 = s2+c3;
  lds[t] = s3;
  __syncthreads();
  for (int off=1; off<1024; off<<=1){
    int v = lds[t];
    int add = (t>=off)? lds[t-off] : 0;
    __syncthreads();
    lds[t] = v + add;
    __syncthreads();
  }
  int incl = lds[t];
  int base = incl - s3;
  offsets[4*t+0]=base;    offsets[4*t+1]=base+c0; offsets[4*t+2]=base+s1; offsets[4*t+3]=base+s2;
  cursor [4*t+0]=base;    cursor [4*t+1]=base+c0; cursor [4*t+2]=base+s1; cursor [4*t+3]=base+s2;
  if (t==1023) offsets[4096]=incl;
}

__global__ void __launch_bounds__(256) k_fill(const int* __restrict__ dst, const int* __restrict__ src,
                                              int* __restrict__ cursor,
                                              int* __restrict__ pos, int* __restrict__ csrc){
  int e = blockIdx.x*256 + threadIdx.x;
  if (e < NE){
    int p = atomicAdd(&cursor[dst[e]], 1);
    pos[e] = p;
    csrc[p] = src[e];
  }
}

// ---------------- edge geometry ----------------
template<typename T>
__device__ __forceinline__ void geom_impl(const T* ew, const T* evec,
    const int* src, const int* dst, const int* pos, float* gC, float* gVp){
  int e = blockIdx.x*256 + threadIdx.x;
  if (e >= NE) return;
  float d = ldf(ew, e);
  float c = 0.5f*(cosf(d*0.6283185307179586f)+1.0f);
  c = (d < 5.0f) ? c : 0.0f;
  gC[e] = c;
  float x = ldf(evec, (size_t)e*3+0), y = ldf(evec, (size_t)e*3+1), z = ldf(evec, (size_t)e*3+2);
  if (src[e] != dst[e]){
    float n = sqrtf(x*x+y*y+z*z);
    float inv = 1.0f/fmaxf(n, 1e-12f);
    x*=inv; y*=inv; z*=inv;
  }
  int p = pos[e];
  gVp[p*3+0]=x; gVp[p*3+1]=y; gVp[p*3+2]=z;
}
__global__ void __launch_bounds__(256) k_geom(const void* ew, const void* evec,
    const int* __restrict__ src, const int* __restrict__ dst, const int* __restrict__ pos,
    float* __restrict__ gC, float* __restrict__ gVp, const int* __restrict__ flag){
  if (flag[0]) geom_impl<float>((const float*)ew, (const float*)evec, src, dst, pos, gC, gVp);
  else         geom_impl<bf16 >((const bf16* )ew, (const bf16* )evec, src, dst, pos, gC, gVp);
}

// ---------------- per-z embedding products ----------------
template<typename T>
__device__ __forceinline__ void zemb_impl(const T* emb, const T* emb2_w,
    float* P1z, float* P2z, float* Zr){
  int zv = blockIdx.x, h = threadIdx.x;
  Zr[h] = ldf(emb, (size_t)zv*HH + h);
  __syncthreads();
  float p1=0.f, p2=0.f;
  for (int r=0;r<128;++r){
    float x = Zr[r];
    p1 += x*ldf(emb2_w, (size_t)r*HH+h);
    p2 += x*ldf(emb2_w, (size_t)(r+128)*HH+h);
  }
  P1z[zv*HH+h]=p1; P2z[zv*HH+h]=p2;
}
__global__ void __launch_bounds__(128) k_zemb(const void* emb, const void* emb2_w,
    float* __restrict__ P1z, float* __restrict__ P2z, const int* __restrict__ flag){
  __shared__ float Zr[128];
  if (flag[0]) zemb_impl<float>((const float*)emb, (const float*)emb2_w, P1z, P2z, Zr);
  else         zemb_impl<bf16 >((const bf16* )emb, (const bf16* )emb2_w, P1z, P2z, Zr);
}

// ---------------- convert edge_attr -> bf16 ----------------
__global__ void __launch_bounds__(256) k_cvt_attr(const void* in, unsigned short* __restrict__ out,
                                                  const int* __restrict__ flag){
  int i = blockIdx.x*256 + threadIdx.x;
  if (flag[0]) out[i] = f2bu(((const float*)in)[i]);
  else         out[i] = ((const unsigned short*)in)[i];
}

// ---------------- weight repack into MFMA B-fragment layout (23 matrices) ----------------
struct PackDescs {
  const void*     base[23];
  long            eoff[23];
  unsigned short* out[23];
  int K[23]; int N[23];
};
template<typename T>
__device__ __forceinline__ void pack_impl(const PackDescs& d){
  int y = blockIdx.y;
  int K = d.K[y], N = d.N[y];
  int ktiles = K>>5, ntiles = N>>4;
  int total = ktiles*ntiles*64;
  int idx = blockIdx.x*256 + threadIdx.x;
  if (idx >= total) return;
  int lane = idx & 63, tile = idx >> 6;
  int kt = tile % ktiles, nt = tile / ktiles;
  const T* W = (const T*)d.base[y] + d.eoff[y];
  int n = nt*16 + (lane&15), k0 = kt*32 + (lane>>4)*8;
  unsigned int t[8];
  #pragma unroll
  for (int j=0;j<8;++j) t[j] = f2bu(ldf(W, (size_t)(k0+j)*N + n));
  uint4 v;
  v.x = t[0] | (t[1]<<16);
  v.y = t[2] | (t[3]<<16);
  v.z = t[4] | (t[5]<<16);
  v.w = t[6] | (t[7]<<16);
  *reinterpret_cast<uint4*>(d.out[y] + ((size_t)tile*64 + lane)*8) = v;
}
__global__ void __launch_bounds__(256) k_pack(PackDescs d, const int* __restrict__ flag){
  if (flag[0]) pack_impl<float>(d);
  else         pack_impl<bf16 >(d);
}

// ---------------- TNE edge coefficients -> eabuf bf16 (CSR-ordered rows) ----------------
template<typename T>
__device__ __forceinline__ void tne_edge_impl(
  const T* eattr, const int* src, const int* dst, const int* z, const int* pos,
  const T* dp1_w, const T* dp1_b, const T* dp2_w, const T* dp2_b,
  const T* dp3_w, const T* dp3_b, const T* emb2_b,
  const float* P1z, const float* P2z, const float* gC, bf16* eabuf,
  float (*attr)[32], int* zd, int* zs, int* ppos)
{
  int e0 = blockIdx.x*TPB;
  int h  = threadIdx.x;
  for (int i=h; i<TPB*32; i+=128) attr[i>>5][i&31] = ldf(eattr, (size_t)e0*32 + i);
  if (h < TPB){ int e=e0+h; zd[h]=z[dst[e]]; zs[h]=z[src[e]]; ppos[h]=pos[e]; }
  __syncthreads();
  float w1[TPB], w2[TPB], w3[TPB];
  float b1v=ldf(dp1_b,h), b2v=ldf(dp2_b,h), b3v=ldf(dp3_b,h);
  #pragma unroll
  for (int e=0;e<TPB;++e){ w1[e]=b1v; w2[e]=b2v; w3[e]=b3v; }
  for (int r=0;r<32;++r){
    float u1=ldf(dp1_w,(size_t)r*HH+h), u2=ldf(dp2_w,(size_t)r*HH+h), u3=ldf(dp3_w,(size_t)r*HH+h);
    #pragma unroll
    for (int e=0;e<TPB;++e){ float a=attr[e][r]; w1[e]+=a*u1; w2[e]+=a*u2; w3[e]+=a*u3; }
  }
  float eb = ldf(emb2_b,h);
  #pragma unroll
  for (int e=0;e<TPB;++e){
    float zij = P1z[zd[e]*HH+h] + P2z[zs[e]*HH+h] + eb;
    float c = gC[e0+e];
    bf16* p = eabuf + (size_t)ppos[e]*384;
    p[h]     = __float2bfloat16(zij*w1[e]*c);
    p[128+h] = __float2bfloat16(zij*w2[e]*c);
    p[256+h] = __float2bfloat16(zij*w3[e]*c);
  }
}
__global__ void __launch_bounds__(128) k_tne_edge(
  const void* eattr, const int* __restrict__ src, const int* __restrict__ dst,
  const int* __restrict__ z, const int* __restrict__ pos,
  const void* dp1_w, const void* dp1_b, const void* dp2_w, const void* dp2_b,
  const void* dp3_w, const void* dp3_b, const void* emb2_b,
  const float* __restrict__ P1z, const float* __restrict__ P2z,
  const float* __restrict__ gC, bf16* __restrict__ eabuf, const int* __restrict__ flag)
{
  __shared__ float attr[TPB][32];
  __shared__ int zd[TPB], zs[TPB], ppos[TPB];
  if (flag[0]) tne_edge_impl<float>((const float*)eattr, src, dst, z, pos,
      (const float*)dp1_w, (const float*)dp1_b, (const float*)dp2_w, (const float*)dp2_b,
      (const float*)dp3_w, (const float*)dp3_b, (const float*)emb2_b, P1z, P2z, gC, eabuf, attr, zd, zs, ppos);
  else tne_edge_impl<bf16>((const bf16*)eattr, src, dst, z, pos,
      (const bf16*)dp1_w, (const bf16*)dp1_b, (const bf16*)dp2_w, (const bf16*)dp2_b,
      (const bf16*)dp3_w, (const bf16*)dp3_b, (const bf16*)emb2_b, P1z, P2z, gC, eabuf, attr, zd, zs, ppos);
}

// ---------------- TNE scatter + LN: writes sm10 bf16 and ln bf16 ----------------
template<typename T>
__device__ __forceinline__ void tne_scat_impl(
  const int* offsets, const float* gVp, const bf16* eabuf,
  const T* ln_g, const T* ln_b, bf16* sm10, bf16* lnO, float* red)
{
  int n0 = blockIdx.x*NB, h = threadIdx.x;
  float tnv[NB];
  #pragma unroll
  for (int nn=0;nn<NB;++nn){
    int n = n0+nn;
    float a=0, v0=0,v1=0,v2=0, s0=0,s1=0,s2=0,s3=0,s4=0,s5=0;
    int beg = offsets[n], end = offsets[n+1];
    int i = beg;
    for (; i+4 <= end; i += 4){
      float c1[4],c2[4],c3[4],vx[4],vy[4],vz[4];
      #pragma unroll
      for (int u=0;u<4;++u){
        const bf16* p = eabuf + (size_t)(i+u)*384;
        c1[u]=b2f(p[h]); c2[u]=b2f(p[128+h]); c3[u]=b2f(p[256+h]);
        vx[u]=gVp[(i+u)*3+0]; vy[u]=gVp[(i+u)*3+1]; vz[u]=gVp[(i+u)*3+2];
      }
      #pragma unroll
      for (int u=0;u<4;++u){
        float tr3 = (vx[u]*vx[u]+vy[u]*vy[u]+vz[u]*vz[u])*(1.0f/3.0f);
        a  += c1[u];
        v0 += c2[u]*vx[u]; v1 += c2[u]*vy[u]; v2 += c2[u]*vz[u];
        s0 += c3[u]*(vx[u]*vx[u] - tr3); s1 += c3[u]*vx[u]*vy[u]; s2 += c3[u]*vx[u]*vz[u];
        s3 += c3[u]*(vy[u]*vy[u] - tr3); s4 += c3[u]*vy[u]*vz[u]; s5 += c3[u]*(vz[u]*vz[u] - tr3);
      }
    }
    for (; i<end; ++i){
      const bf16* p = eabuf + (size_t)i*384;
      float c1 = b2f(p[h]), c2 = b2f(p[128+h]), c3 = b2f(p[256+h]);
      float vx = gVp[i*3+0], vy = gVp[i*3+1], vz = gVp[i*3+2];
      float tr3 = (vx*vx+vy*vy+vz*vz)*(1.0f/3.0f);
      a  += c1;
      v0 += c2*vx; v1 += c2*vy; v2 += c2*vz;
      s0 += c3*(vx*vx - tr3); s1 += c3*vx*vy;          s2 += c3*vx*vz;
      s3 += c3*(vy*vy - tr3); s4 += c3*vy*vz;          s5 += c3*(vz*vz - tr3);
    }
    bf16* sp = sm10 + (size_t)n*1280;
    sp[0*128+h]=__float2bfloat16(a);
    sp[1*128+h]=__float2bfloat16(v0); sp[2*128+h]=__float2bfloat16(v1); sp[3*128+h]=__float2bfloat16(v2);
    sp[4*128+h]=__float2bfloat16(s0); sp[5*128+h]=__float2bfloat16(s1); sp[6*128+h]=__float2bfloat16(s2);
    sp[7*128+h]=__float2bfloat16(s3); sp[8*128+h]=__float2bfloat16(s4); sp[9*128+h]=__float2bfloat16(s5);
    tnv[nn] = 3.0f*a*a + 2.0f*(v0*v0+v1*v1+v2*v2)
            + s0*s0 + s3*s3 + s5*s5 + 2.0f*(s1*s1 + s2*s2 + s4*s4);
  }
  float gg = ldf(ln_g,h), bb = ldf(ln_b,h);
  #pragma unroll
  for (int nn=0;nn<NB;++nn){
    __syncthreads();
    red[h] = tnv[nn]; __syncthreads();
    for (int off=64; off>=1; off>>=1){ if (h<off) red[h]+=red[h+off]; __syncthreads(); }
    float mean = red[0]*(1.0f/128.0f);
    __syncthreads();
    float dm = tnv[nn] - mean;
    red[h] = dm*dm; __syncthreads();
    for (int off=64; off>=1; off>>=1){ if (h<off) red[h]+=red[h+off]; __syncthreads(); }
    float var = red[0]*(1.0f/128.0f);
    lnO[(size_t)(n0+nn)*128 + h] = __float2bfloat16(dm*rsqrtf(var+1e-5f)*gg + bb);
  }
}
__global__ void __launch_bounds__(128) k_tne_scat(
  const int* __restrict__ offsets, const float* __restrict__ gVp, const bf16* __restrict__ eabuf,
  const void* ln_g, const void* ln_b, bf16* __restrict__ sm10, bf16* __restrict__ lnO,
  const int* __restrict__ flag)
{
  __shared__ float red[128];
  if (flag[0]) tne_scat_impl<float>(offsets, gVp, eabuf, (const float*)ln_g, (const float*)ln_b, sm10, lnO, red);
  else         tne_scat_impl<bf16 >(offsets, gVp, eabuf, (const bf16* )ln_g, (const bf16* )ln_b, sm10, lnO, red);
}

// ---------------- node fsc MLP via MFMA (r17-validated) ----------------
template<typename T>
__device__ __forceinline__ void node_mlp_impl(
  const bf16* lnO, const unsigned short* ps0, const unsigned short* ps1,
  const T* b0, const T* b1, bf16* fsc3, unsigned short* h2p)
{
  int wid  = threadIdx.x >> 6;
  int lane = threadIdx.x & 63;
  int n0 = blockIdx.x*16;
  int m = lane & 15, g = lane >> 4;
  short8v aln[4];
  #pragma unroll
  for (int ks=0; ks<4; ++ks)
    aln[ks] = *reinterpret_cast<const short8v*>((const unsigned short*)lnO + (size_t)(n0+m)*128 + ks*32 + g*8);
  for (int nt=wid; nt<16; nt+=4){
    float bias = ldf(b0, nt*16+m);
    f32x4 acc = {bias,bias,bias,bias};
    #pragma unroll
    for (int ks=0; ks<4; ++ks){
      short8v b = *reinterpret_cast<const short8v*>(ps0 + ((size_t)(nt*4+ks)*64 + lane)*8);
      acc = __builtin_amdgcn_mfma_f32_16x16x32_bf16(aln[ks], b, acc, 0,0,0);
    }
    #pragma unroll
    for (int r=0;r<4;++r){
      int n = nt*16 + m, row = g*4 + r;
      h2p[(n>>5)*512 + (((n>>3)&3)*16+row)*8 + (n&7)] = f2bu(siluf(acc[r]));
    }
  }
  __syncthreads();
  short8v a3[8];
  #pragma unroll
  for (int ks=0; ks<8; ++ks) a3[ks] = *reinterpret_cast<const short8v*>(&h2p[ks*512 + lane*8]);
  for (int nt=wid; nt<24; nt+=4){
    float bias = ldf(b1, nt*16+m);
    f32x4 acc = {bias,bias,bias,bias};
    #pragma unroll
    for (int ks=0; ks<8; ++ks){
      short8v b = *reinterpret_cast<const short8v*>(ps1 + ((size_t)(nt*8+ks)*64 + lane)*8);
      acc = __builtin_amdgcn_mfma_f32_16x16x32_bf16(a3[ks], b, acc, 0,0,0);
    }
    #pragma unroll
    for (int r=0;r<4;++r){
      int n = nt*16 + m, row = g*4 + r;
      ((unsigned short*)fsc3)[(size_t)(n0+row)*384 + (n%3)*128 + (n/3)] = f2bu(siluf(acc[r]));
    }
  }
}
__global__ void __launch_bounds__(256) k_node_mlp(
  const bf16* __restrict__ lnO, const unsigned short* __restrict__ ps0,
  const unsigned short* __restrict__ ps1,
  const void* b0, const void* b1, bf16* __restrict__ fsc3, const int* __restrict__ flag)
{
  __shared__ __align__(16) unsigned short h2p[4096];
  if (flag[0]) node_mlp_impl<float>(lnO, ps0, ps1, (const float*)b0, (const float*)b1, fsc3, h2p);
  else         node_mlp_impl<bf16 >(lnO, ps0, ps1, (const bf16* )b0, (const bf16* )b1, fsc3, h2p);
}

// ---------------- tne cmix via MFMA + fsc combine -> X9 (r17-validated) ----------------
__global__ void __launch_bounds__(256) k_tne_cmix(
  const bf16* __restrict__ sm10, const unsigned short* __restrict__ pwlt,
  const bf16* __restrict__ fsc3, float* __restrict__ X9)
{
  int wid  = threadIdx.x >> 6;
  int lane = threadIdx.x & 63;
  int n0 = blockIdx.x*16;
  int m = lane & 15, g = lane >> 4;
  f32x4 acc[10][2];
  #pragma unroll
  for (int c=0;c<10;++c){ acc[c][0]=(f32x4){0,0,0,0}; acc[c][1]=(f32x4){0,0,0,0}; }
  #pragma unroll
  for (int c=0;c<10;++c){
    int mat = (c==0) ? 0 : (c<4) ? 1 : 2;
    const unsigned short* bw = pwlt + (size_t)mat*16384;
    short8v af[4];
    #pragma unroll
    for (int ks=0; ks<4; ++ks)
      af[ks] = *reinterpret_cast<const short8v*>((const unsigned short*)sm10 + (size_t)(n0+m)*1280 + c*128 + ks*32 + g*8);
    #pragma unroll
    for (int t=0;t<2;++t){
      int nt = wid + t*4;
      #pragma unroll
      for (int ks=0; ks<4; ++ks){
        short8v b = *reinterpret_cast<const short8v*>(bw + ((size_t)(nt*4+ks)*64 + lane)*8);
        acc[c][t] = __builtin_amdgcn_mfma_f32_16x16x32_bf16(af[ks], b, acc[c][t], 0,0,0);
      }
    }
  }
  #pragma unroll
  for (int t=0;t<2;++t){
    int nt = wid + t*4;
    int h = nt*16 + m;
    #pragma unroll
    for (int r=0;r<4;++r){
      int node = n0 + g*4 + r;
      float am  = acc[0][t][r];
      float wm0 = acc[1][t][r], wm1 = acc[2][t][r], wm2 = acc[3][t][r];
      float t0 = acc[4][t][r], t1 = acc[5][t][r], t2 = acc[6][t][r];
      float t3 = acc[7][t][r], t4 = acc[8][t][r], t5 = acc[9][t][r];
      float f0 = b2f(fsc3[(size_t)node*384 + h]);
      float f1 = b2f(fsc3[(size_t)node*384 + 128 + h]);
      float f2 = b2f(fsc3[(size_t)node*384 + 256 + h]);
      float* xp = X9 + (size_t)node*1152;
      xp[0*128+h] = f0*am + f2*t0;
      xp[1*128+h] = -f1*wm2 + f2*t1;
      xp[2*128+h] =  f1*wm1 + f2*t2;
      xp[3*128+h] =  f1*wm2 + f2*t1;
      xp[4*128+h] = f0*am + f2*t3;
      xp[5*128+h] = -f1*wm0 + f2*t4;
      xp[6*128+h] = -f1*wm1 + f2*t2;
      xp[7*128+h] =  f1*wm0 + f2*t4;
      xp[8*128+h] = f0*am + f2*t5;
    }
  }
}

// ---------------- FUSED: normalize X (16 nodes) + cmix(lx) via MFMA -> Y10 ----------------
__global__ void __launch_bounds__(256) k_cmix_norm(
  float* __restrict__ X9, const unsigned short* __restrict__ pw, bf16* __restrict__ Y10)
{
  __shared__ __align__(16) unsigned short sst[16*1280];   // 40 KB
  int n0 = blockIdx.x*16;
  int tid = threadIdx.x;
  #pragma unroll
  for (int it=0; it<8; ++it){
    int idx = it*256 + tid;          // 0..2047
    int nn = idx >> 7, h = idx & 127;
    float* xp = X9 + (size_t)(n0+nn)*1152;
    float x00=xp[0*128+h], x01=xp[1*128+h], x02=xp[2*128+h];
    float x10=xp[3*128+h], x11=xp[4*128+h], x12=xp[5*128+h];
    float x20=xp[6*128+h], x21=xp[7*128+h], x22=xp[8*128+h];
    float tn = x00*x00+x01*x01+x02*x02+x10*x10+x11*x11+x12*x12+x20*x20+x21*x21+x22*x22;
    float inv = __builtin_amdgcn_rcpf(tn+1.0f);
    x00*=inv; x01*=inv; x02*=inv; x10*=inv; x11*=inv; x12*=inv; x20*=inv; x21*=inv; x22*=inv;
    xp[0*128+h]=x00; xp[1*128+h]=x01; xp[2*128+h]=x02;
    xp[3*128+h]=x10; xp[4*128+h]=x11; xp[5*128+h]=x12;
    xp[6*128+h]=x20; xp[7*128+h]=x21; xp[8*128+h]=x22;
    float a = (x00+x11+x22)*(1.0f/3.0f);
    unsigned short* sp = sst + (size_t)nn*1280;
    sp[0*128+h]=f2bu(a);
    sp[1*128+h]=f2bu(0.5f*(x21-x12));
    sp[2*128+h]=f2bu(0.5f*(x02-x20));
    sp[3*128+h]=f2bu(0.5f*(x10-x01));
    sp[4*128+h]=f2bu(x00-a);
    sp[5*128+h]=f2bu(0.5f*(x01+x10));
    sp[6*128+h]=f2bu(0.5f*(x02+x20));
    sp[7*128+h]=f2bu(x11-a);
    sp[8*128+h]=f2bu(0.5f*(x12+x21));
    sp[9*128+h]=f2bu(x22-a);
  }
  __syncthreads();
  int wid  = tid >> 6;
  int lane = tid & 63;
  int m = lane & 15, g = lane >> 4;
  f32x4 acc[10][2];
  #pragma unroll
  for (int c=0;c<10;++c){ acc[c][0]=(f32x4){0,0,0,0}; acc[c][1]=(f32x4){0,0,0,0}; }
  #pragma unroll
  for (int c=0;c<10;++c){
    int mat = (c==0) ? 0 : (c<4) ? 1 : 2;
    const unsigned short* bw = pw + (size_t)mat*16384;
    short8v af[4];
    #pragma unroll
    for (int ks=0; ks<4; ++ks)
      af[ks] = *reinterpret_cast<const short8v*>(&sst[(size_t)m*1280 + c*128 + ks*32 + g*8]);
    #pragma unroll
    for (int t=0;t<2;++t){
      int nt = wid + t*4;
      #pragma unroll
      for (int ks=0; ks<4; ++ks){
        short8v b = *reinterpret_cast<const short8v*>(bw + ((size_t)(nt*4+ks)*64 + lane)*8);
        acc[c][t] = __builtin_amdgcn_mfma_f32_16x16x32_bf16(af[ks], b, acc[c][t], 0,0,0);
      }
    }
  }
  #pragma unroll
  for (int t=0;t<2;++t){
    int nt = wid + t*4;
    int h = nt*16 + m;
    #pragma unroll
    for (int r=0;r<4;++r){
      int node = n0 + g*4 + r;
      unsigned short* op = (unsigned short*)Y10 + (size_t)node*1280;
      #pragma unroll
      for (int c=0;c<10;++c) op[c*128 + h] = f2bu(acc[c][t][r]);
    }
  }
}

// ---------------- msg edge MLP via MFMA: 16 edges/block, both layers (blockIdx.y),
// LDS output staging (seg stride 136, row stride 408 — bank de-aliased) ----------------
template<typename T>
__device__ __forceinline__ void mfma_impl(
  const unsigned short* eattr_c, const float* gC, const int* pos,
  const unsigned short* p0, const unsigned short* p1, const unsigned short* p2,
  const T* b0, const T* b1, const T* b2,
  unsigned short* eabuf, unsigned short* buf, int* spos)
{
  int wid  = threadIdx.x >> 6;
  int lane = threadIdx.x & 63;
  int e0 = blockIdx.x*16;
  int m = lane & 15, g = lane >> 4;
  if (threadIdx.x < 16) spos[threadIdx.x] = pos[e0 + threadIdx.x];
  float cc[4];
  #pragma unroll
  for (int r=0;r<4;++r) cc[r] = gC[e0 + g*4 + r];
  unsigned short* h1p = buf;
  unsigned short* h2p = buf + 2048;
  short8v a1 = *reinterpret_cast<const short8v*>(eattr_c + (size_t)(e0+m)*32 + g*8);
  // l0: 8 nt tiles, 2 per wave
  for (int nt=wid; nt<8; nt+=4){
    float bias = ldf(b0, nt*16+m);
    f32x4 acc = {bias,bias,bias,bias};
    short8v b = *reinterpret_cast<const short8v*>(p0 + ((size_t)nt*64 + lane)*8);
    acc = __builtin_amdgcn_mfma_f32_16x16x32_bf16(a1, b, acc, 0,0,0);
    #pragma unroll
    for (int r=0;r<4;++r){
      int n = nt*16 + m, row = g*4 + r;
      h1p[(n>>5)*512 + (((n>>3)&3)*16+row)*8 + (n&7)] = f2bu(siluf(acc[r]));
    }
  }
  __syncthreads();
  short8v a2[4];
  #pragma unroll
  for (int ks=0; ks<4; ++ks) a2[ks] = *reinterpret_cast<const short8v*>(&h1p[ks*512 + lane*8]);
  // l1: 16 nt tiles, 4 per wave
  for (int nt=wid; nt<16; nt+=4){
    float bias = ldf(b1, nt*16+m);
    f32x4 acc = {bias,bias,bias,bias};
    #pragma unroll
    for (int ks=0; ks<4; ++ks){
      short8v b = *reinterpret_cast<const short8v*>(p1 + ((size_t)(nt*4+ks)*64 + lane)*8);
      acc = __builtin_amdgcn_mfma_f32_16x16x32_bf16(a2[ks], b, acc, 0,0,0);
    }
    #pragma unroll
    for (int r=0;r<4;++r){
      int n = nt*16 + m, row = g*4 + r;
      h2p[(n>>5)*512 + (((n>>3)&3)*16+row)*8 + (n&7)] = f2bu(siluf(acc[r]));
    }
  }
  __syncthreads();
  short8v a3[8];
  #pragma unroll
  for (int ks=0; ks<8; ++ks) a3[ks] = *reinterpret_cast<const short8v*>(&h2p[ks*512 + lane*8]);
  __syncthreads();   // all waves hold a3 in regs; buf is now free for ostage
  // l2: 24 nt tiles, 6 per wave -> ostage (row stride 408, seg stride 136)
  for (int nt=wid; nt<24; nt+=4){
    float bias = ldf(b2, nt*16+m);
    f32x4 acc = {bias,bias,bias,bias};
    #pragma unroll
    for (int ks=0; ks<8; ++ks){
      short8v b = *reinterpret_cast<const short8v*>(p2 + ((size_t)(nt*8+ks)*64 + lane)*8);
      acc = __builtin_amdgcn_mfma_f32_16x16x32_bf16(a3[ks], b, acc, 0,0,0);
    }
    #pragma unroll
    for (int r=0;r<4;++r){
      int n = nt*16 + m, row = g*4 + r;
      float v = siluf(acc[r]) * cc[r];
      buf[row*408 + (n%3)*136 + (n/3)] = f2bu(v);
    }
  }
  __syncthreads();
  // coalesced write-out: 16 threads per row, 3 segments x uint4 each (768B/row)
  int r  = threadIdx.x >> 4;
  int ch = threadIdx.x & 15;
  size_t base = (size_t)spos[r]*384;
  #pragma unroll
  for (int seg=0; seg<3; ++seg){
    uint4 v = *reinterpret_cast<const uint4*>(&buf[r*408 + seg*136 + ch*8]);
    *reinterpret_cast<uint4*>(eabuf + base + (size_t)(seg*128 + ch*8)) = v;
  }
}
__global__ void __launch_bounds__(256) k_msg_edge_mfma(
  const unsigned short* __restrict__ eattr_c, const float* __restrict__ gC,
  const int* __restrict__ pos,
  const unsigned short* __restrict__ p0a, const unsigned short* __restrict__ p0b,
  const unsigned short* __restrict__ p1a, const unsigned short* __restrict__ p1b,
  const unsigned short* __restrict__ p2a, const unsigned short* __restrict__ p2b,
  const void* b0, const void* b1, const void* b2,
  unsigned short* __restrict__ eabuf_msg, const int* __restrict__ flag)
{
  __shared__ __align__(16) unsigned short buf[6528];   // max(h1p+h2p=6144, ostage 16*408=6528)
  __shared__ int spos[16];
  int l = blockIdx.y;
  const unsigned short* p0 = l ? p0b : p0a;
  const unsigned short* p1 = l ? p1b : p1a;
  const unsigned short* p2 = l ? p2b : p2a;
  unsigned short* eabuf = eabuf_msg + (size_t)l*NE*384;
  if (flag[0]) mfma_impl<float>(eattr_c, gC, pos, p0, p1, p2,
      (const float*)b0 + (long)l*128, (const float*)b1 + (long)l*256, (const float*)b2 + (long)l*384,
      eabuf, buf, spos);
  else mfma_impl<bf16>(eattr_c, gC, pos, p0, p1, p2,
      (const bf16*)b0 + (long)l*128, (const bf16*)b1 + (long)l*256, (const bf16*)b2 + (long)l*384,
      eabuf, buf, spos);
}

// ---------------- msg scatter + AB + decompose -> smb bf16 ----------------
__global__ void __launch_bounds__(128) k_msg_sab(
  const int* __restrict__ offsets, const int* __restrict__ csrc,
  const bf16* __restrict__ eabuf, const bf16* __restrict__ Y10, bf16* __restrict__ smb)
{
  int n0 = blockIdx.x*NB, h = threadIdx.x;
  #pragma unroll
  for (int nn=0;nn<NB;++nn){
    int n = n0+nn;
    float am=0, vm0=0,vm1=0,vm2=0, smm0=0,smm1=0,smm2=0,smm3=0,smm4=0,smm5=0;
    int beg = offsets[n], end = offsets[n+1];
    int i = beg;
    for (; i+4 <= end; i += 4){
      int ss[4];
      #pragma unroll
      for (int u=0;u<4;++u){ ss[u] = csrc[i+u]; }
      float e0a[4], e1a[4], e2a[4];
      float y0[4],y1[4],y2[4],y3[4],y4[4],y5[4],y6[4],y7[4],y8[4],y9[4];
      #pragma unroll
      for (int u=0;u<4;++u){
        const bf16* ep = eabuf + (size_t)(i+u)*384;
        e0a[u]=b2f(ep[h]); e1a[u]=b2f(ep[128+h]); e2a[u]=b2f(ep[256+h]);
        const bf16* yp = Y10 + (size_t)ss[u]*1280;
        y0[u]=b2f(yp[0*128+h]); y1[u]=b2f(yp[1*128+h]); y2[u]=b2f(yp[2*128+h]);
        y3[u]=b2f(yp[3*128+h]); y4[u]=b2f(yp[4*128+h]); y5[u]=b2f(yp[5*128+h]);
        y6[u]=b2f(yp[6*128+h]); y7[u]=b2f(yp[7*128+h]); y8[u]=b2f(yp[8*128+h]);
        y9[u]=b2f(yp[9*128+h]);
      }
      #pragma unroll
      for (int u=0;u<4;++u){
        am   += e0a[u]*y0[u];
        vm0  += e1a[u]*y1[u]; vm1 += e1a[u]*y2[u]; vm2 += e1a[u]*y3[u];
        smm0 += e2a[u]*y4[u]; smm1 += e2a[u]*y5[u]; smm2 += e2a[u]*y6[u];
        smm3 += e2a[u]*y7[u]; smm4 += e2a[u]*y8[u]; smm5 += e2a[u]*y9[u];
      }
    }
    for (; i<end; ++i){
      int s = csrc[i];
      const bf16* ep = eabuf + (size_t)i*384;
      float e0 = b2f(ep[h]), e1 = b2f(ep[128+h]), e2 = b2f(ep[256+h]);
      const bf16* yp = Y10 + (size_t)s*1280;
      am   += e0*b2f(yp[0*128+h]);
      vm0  += e1*b2f(yp[1*128+h]); vm1 += e1*b2f(yp[2*128+h]); vm2 += e1*b2f(yp[3*128+h]);
      smm0 += e2*b2f(yp[4*128+h]); smm1 += e2*b2f(yp[5*128+h]); smm2 += e2*b2f(yp[6*128+h]);
      smm3 += e2*b2f(yp[7*128+h]); smm4 += e2*b2f(yp[8*128+h]); smm5 += e2*b2f(yp[9*128+h]);
    }
    const bf16* yp = Y10 + (size_t)n*1280;
    float aY=b2f(yp[0*128+h]), u0=b2f(yp[1*128+h]), u1=b2f(yp[2*128+h]), u2=b2f(yp[3*128+h]);
    float q0=b2f(yp[4*128+h]), q1=b2f(yp[5*128+h]), q2=b2f(yp[6*128+h]);
    float q3=b2f(yp[7*128+h]), q4=b2f(yp[8*128+h]), q5=b2f(yp[9*128+h]);
    float m00=am+smm0,   m01=-vm2+smm1, m02= vm1+smm2;
    float m10= vm2+smm1, m11=am+smm3,  m12=-vm0+smm4;
    float m20=-vm1+smm2, m21= vm0+smm4, m22=am+smm5;
    float y00=aY+q0,  y01=-u2+q1, y02= u1+q2;
    float y10= u2+q1, y11=aY+q3,  y12=-u0+q4;
    float y20=-u1+q2, y21= u0+q4, y22=aY+q5;
    float ab00 = m00*y00+m01*y10+m02*y20 + y00*m00+y01*m10+y02*m20;
    float ab01 = m00*y01+m01*y11+m02*y21 + y00*m01+y01*m11+y02*m21;
    float ab02 = m00*y02+m01*y12+m02*y22 + y00*m02+y01*m12+y02*m22;
    float ab10 = m10*y00+m11*y10+m12*y20 + y10*m00+y11*m10+y12*m20;
    float ab11 = m10*y01+m11*y11+m12*y21 + y10*m01+y11*m11+y12*m21;
    float ab12 = m10*y02+m11*y12+m12*y22 + y10*m02+y11*m12+y12*m22;
    float ab20 = m20*y00+m21*y10+m22*y20 + y20*m00+y21*m10+y22*m20;
    float ab21 = m20*y01+m21*y11+m22*y21 + y20*m01+y21*m11+y22*m21;
    float ab22 = m20*y02+m21*y12+m22*y22 + y20*m02+y21*m12+y22*m22;
    float a2 = (ab00+ab11+ab22)*(1.0f/3.0f);
    float w0 = 0.5f*(ab21-ab12), w1 = 0.5f*(ab02-ab20), w2 = 0.5f*(ab10-ab01);
    float t0 = ab00-a2, t1 = 0.5f*(ab01+ab10), t2 = 0.5f*(ab02+ab20);
    float t3 = ab11-a2, t4 = 0.5f*(ab12+ab21), t5 = ab22-a2;
    float dnm = ab00*ab00+ab01*ab01+ab02*ab02+ab10*ab10+ab11*ab11+ab12*ab12
              + ab20*ab20+ab21*ab21+ab22*ab22 + 1.0f;
    float inv = __builtin_amdgcn_rcpf(dnm);
    bf16* sp = smb + (size_t)n*1280;
    sp[0*128+h]=__float2bfloat16(a2*inv);
    sp[1*128+h]=__float2bfloat16(w0*inv); sp[2*128+h]=__float2bfloat16(w1*inv); sp[3*128+h]=__float2bfloat16(w2*inv);
    sp[4*128+h]=__float2bfloat16(t0*inv); sp[5*128+h]=__float2bfloat16(t1*inv); sp[6*128+h]=__float2bfloat16(t2*inv);
    sp[7*128+h]=__float2bfloat16(t3*inv); sp[8*128+h]=__float2bfloat16(t4*inv); sp[9*128+h]=__float2bfloat16(t5*inv);
  }
}

// ---------------- FUSED: cmix(lt) via MFMA + dX+dX^2 + X update / output ----------------
template<typename T>
__device__ __forceinline__ void cmix_fin_impl(
  const bf16* smb, const unsigned short* pw, float* X9, T* out, int write_out)
{
  int wid  = threadIdx.x >> 6;
  int lane = threadIdx.x & 63;
  int n0 = blockIdx.x*16;
  int m = lane & 15, g = lane >> 4;
  f32x4 acc[10][2];
  #pragma unroll
  for (int c=0;c<10;++c){ acc[c][0]=(f32x4){0,0,0,0}; acc[c][1]=(f32x4){0,0,0,0}; }
  #pragma unroll
  for (int c=0;c<10;++c){
    int mat = (c==0) ? 0 : (c<4) ? 1 : 2;
    const unsigned short* bw = pw + (size_t)mat*16384;
    short8v af[4];
    #pragma unroll
    for (int ks=0; ks<4; ++ks)
      af[ks] = *reinterpret_cast<const short8v*>((const unsigned short*)smb + (size_t)(n0+m)*1280 + c*128 + ks*32 + g*8);
    #pragma unroll
    for (int t=0;t<2;++t){
      int nt = wid + t*4;
      #pragma unroll
      for (int ks=0; ks<4; ++ks){
        short8v b = *reinterpret_cast<const short8v*>(bw + ((size_t)(nt*4+ks)*64 + lane)*8);
        acc[c][t] = __builtin_amdgcn_mfma_f32_16x16x32_bf16(af[ks], b, acc[c][t], 0,0,0);
      }
    }
  }
  #pragma unroll
  for (int t=0;t<2;++t){
    int nt = wid + t*4;
    int h = nt*16 + m;
    #pragma unroll
    for (int r=0;r<4;++r){
      int node = n0 + g*4 + r;
      float at  = bround(acc[0][t][r]);
      float vt0 = bround(acc[1][t][r]), vt1 = bround(acc[2][t][r]), vt2 = bround(acc[3][t][r]);
      float st0 = bround(acc[4][t][r]), st1 = bround(acc[5][t][r]), st2 = bround(acc[6][t][r]);
      float st3 = bround(acc[7][t][r]), st4 = bround(acc[8][t][r]), st5 = bround(acc[9][t][r]);
      float d00=at+st0,   d01=-vt2+st1, d02= vt1+st2;
      float d10= vt2+st1, d11=at+st3,  d12=-vt0+st4;
      float d20=-vt1+st2, d21= vt0+st4, d22=at+st5;
      float g00 = d00 + d00*d00+d01*d10+d02*d20;
      float g01 = d01 + d00*d01+d01*d11+d02*d21;
      float g02 = d02 + d00*d02+d01*d12+d02*d22;
      float g10 = d10 + d10*d00+d11*d10+d12*d20;
      float g11 = d11 + d10*d01+d11*d11+d12*d21;
      float g12 = d12 + d10*d02+d11*d12+d12*d22;
      float g20 = d20 + d20*d00+d21*d10+d22*d20;
      float g21 = d21 + d20*d01+d21*d11+d22*d21;
      float g22 = d22 + d20*d02+d21*d12+d22*d22;
      float* xp = X9 + (size_t)node*1152;
      float x00=xp[0*128+h]+g00, x01=xp[1*128+h]+g01, x02=xp[2*128+h]+g02;
      float x10=xp[3*128+h]+g10, x11=xp[4*128+h]+g11, x12=xp[5*128+h]+g12;
      float x20=xp[6*128+h]+g20, x21=xp[7*128+h]+g21, x22=xp[8*128+h]+g22;
      if (write_out){
        if (sizeof(T)==4){
          float* of = (float*)out + ((size_t)node*128 + h)*9;
          of[0]=x00; of[1]=x01; of[2]=x02; of[3]=x10; of[4]=x11; of[5]=x12; of[6]=x20; of[7]=x21; of[8]=x22;
        } else {
          bf16* ob = (bf16*)out + ((size_t)node*128 + h)*9;
          ob[0]=__float2bfloat16(x00); ob[1]=__float2bfloat16(x01); ob[2]=__float2bfloat16(x02);
          ob[3]=__float2bfloat16(x10); ob[4]=__float2bfloat16(x11); ob[5]=__float2bfloat16(x12);
          ob[6]=__float2bfloat16(x20); ob[7]=__float2bfloat16(x21); ob[8]=__float2bfloat16(x22);
        }
      } else {
        xp[0*128+h]=x00; xp[1*128+h]=x01; xp[2*128+h]=x02;
        xp[3*128+h]=x10; xp[4*128+h]=x11; xp[5*128+h]=x12;
        xp[6*128+h]=x20; xp[7*128+h]=x21; xp[8*128+h]=x22;
      }
    }
  }
}
__global__ void __launch_bounds__(256) k_cmix_fin(
  const bf16* __restrict__ smb, const unsigned short* __restrict__ pw,
  float* __restrict__ X9, void* __restrict__ out,
  const int* __restrict__ flag, int write_out)
{
  if (flag[0]) cmix_fin_impl<float>(smb, pw, X9, (float*)out, write_out);
  else         cmix_fin_impl<bf16 >(smb, pw, X9, (bf16* )out, write_out);
}

extern "C" void kernel_launch(void* const* d_in, const int* in_sizes, int n_in,
                              void* d_out, int out_size, void* d_ws, size_t ws_size,
                              hipStream_t stream)
{
  (void)in_sizes; (void)n_in; (void)out_size; (void)ws_size;
  const int* z    = (const int*)d_in[0];
  const int* eidx = (const int*)d_in[1];
  const int* src  = eidx;
  const int* dst  = eidx + NE;

  // Workspace ~160 MB (ws_size ~256 MB per r19 fillBuffer evidence).
  char* w = (char*)d_ws;
  int* flag    = (int*)w;   w += 64;
  int* counts  = (int*)w;   w += (size_t)NN*4;
  int* offsets = (int*)w;   w += (size_t)(NN+1)*4 + 60;
  int* cursor  = (int*)w;   w += (size_t)NN*4;
  int* pos     = (int*)w;   w += (size_t)NE*4;
  int* csrc    = (int*)w;   w += (size_t)NE*4;
  float* gC    = (float*)w; w += (size_t)NE*4;
  float* gVp   = (float*)w; w += (size_t)NE*12;
  float* P1z   = (float*)w; w += (size_t)MAXZ*HH*4;
  float* P2z   = (float*)w; w += (size_t)MAXZ*HH*4;
  bf16* eabuf  = (bf16*)w;  w += (size_t)NE*384*2;          // tne coefficients
  bf16* eabuf_msg = (bf16*)w; w += (size_t)2*NE*384*2;      // msg edge MLP, both layers
  float* X9    = (float*)w; w += (size_t)NN*1152*4;
  bf16* Y10    = (bf16*)w;  w += (size_t)NN*1280*2;
  bf16* smb    = (bf16*)w;  w += (size_t)NN*1280*2;
  unsigned short* eattr_c = (unsigned short*)w; w += (size_t)NE*32*2;
  unsigned short* pw0[2]; unsigned short* pw1[2]; unsigned short* pw2[2];
  for (int l=0;l<2;++l){
    pw0[l] = (unsigned short*)w; w += 8*64*8*2;
    pw1[l] = (unsigned short*)w; w += 64*64*8*2;
    pw2[l] = (unsigned short*)w; w += 192*64*8*2;
  }
  unsigned short* pw_s0 = (unsigned short*)w; w += 64*64*8*2;
  unsigned short* pw_s1 = (unsigned short*)w; w += 192*64*8*2;
  unsigned short* pwlt  = (unsigned short*)w; w += 3*32*64*8*2;
  unsigned short* pwlx2 = (unsigned short*)w; w += 2*3*32*64*8*2;
  unsigned short* pwlt2 = (unsigned short*)w; w += 2*3*32*64*8*2;
  bf16* lnO    = (bf16*)w;  w += (size_t)NN*128*2;
  bf16* fsc3   = (bf16*)w;  w += (size_t)NN*384*2;
  bf16* sm10   = Y10;   // tne alias: dead until msg cmix_norm overwrites Y10

  k_detect<<<1, 256, 0, stream>>>((const unsigned int*)d_in[4], flag);
  hipMemsetAsync(counts, 0, (size_t)NN*4, stream);
  k_count<<<NE/256, 256, 0, stream>>>(dst, counts);
  k_scan<<<1, 1024, 0, stream>>>(counts, offsets, cursor);
  k_fill<<<NE/256, 256, 0, stream>>>(dst, src, cursor, pos, csrc);
  k_geom<<<NE/256, 256, 0, stream>>>(d_in[2], d_in[3], src, dst, pos, gC, gVp, flag);
  k_zemb<<<MAXZ, 128, 0, stream>>>(d_in[5], d_in[12], P1z, P2z, flag);
  k_cvt_attr<<<NE*32/256, 256, 0, stream>>>(d_in[4], eattr_c, flag);

  PackDescs pd;
  for (int l=0;l<2;++l){
    pd.base[l*3+0] = d_in[21]; pd.eoff[l*3+0] = (long)l*32*128;
    pd.base[l*3+1] = d_in[23]; pd.eoff[l*3+1] = (long)l*128*256;
    pd.base[l*3+2] = d_in[25]; pd.eoff[l*3+2] = (long)l*256*384;
    pd.out[l*3+0] = pw0[l]; pd.K[l*3+0]=32;  pd.N[l*3+0]=128;
    pd.out[l*3+1] = pw1[l]; pd.K[l*3+1]=128; pd.N[l*3+1]=256;
    pd.out[l*3+2] = pw2[l]; pd.K[l*3+2]=256; pd.N[l*3+2]=384;
  }
  pd.base[6] = d_in[15]; pd.eoff[6] = 0; pd.out[6] = pw_s0; pd.K[6]=128; pd.N[6]=256;
  pd.base[7] = d_in[17]; pd.eoff[7] = 0; pd.out[7] = pw_s1; pd.K[7]=256; pd.N[7]=384;
  for (int c=0;c<3;++c){
    pd.base[8+c] = d_in[14]; pd.eoff[8+c] = (long)c*16384;
    pd.out[8+c] = pwlt + (size_t)c*16384; pd.K[8+c]=128; pd.N[8+c]=128;
  }
  for (int l=0;l<2;++l)
    for (int c=0;c<3;++c){
      pd.base[11+l*3+c] = d_in[27]; pd.eoff[11+l*3+c] = (long)(l*3+c)*16384;
      pd.out[11+l*3+c] = pwlx2 + (size_t)(l*3+c)*16384; pd.K[11+l*3+c]=128; pd.N[11+l*3+c]=128;
      pd.base[17+l*3+c] = d_in[28]; pd.eoff[17+l*3+c] = (long)(l*3+c)*16384;
      pd.out[17+l*3+c] = pwlt2 + (size_t)(l*3+c)*16384; pd.K[17+l*3+c]=128; pd.N[17+l*3+c]=128;
    }
  k_pack<<<dim3(48, 23), 256, 0, stream>>>(pd, flag);

  // Both layers' edge MLPs in one dispatch (edge MLP is X-independent).
  k_msg_edge_mfma<<<dim3(NE/16, 2), 256, 0, stream>>>(eattr_c, gC, pos,
      pw0[0], pw0[1], pw1[0], pw1[1], pw2[0], pw2[1],
      d_in[22], d_in[24], d_in[26],
      (unsigned short*)eabuf_msg, flag);

  k_tne_edge<<<NE/TPB, 128, 0, stream>>>(d_in[4], src, dst, z, pos,
      d_in[6], d_in[7], d_in[8], d_in[9], d_in[10], d_in[11], d_in[13],
      P1z, P2z, gC, eabuf, flag);
  k_tne_scat<<<NN/NB, 128, 0, stream>>>(offsets, gVp, eabuf,
      d_in[19], d_in[20], sm10, lnO, flag);
  k_node_mlp<<<NN/16, 256, 0, stream>>>(lnO, pw_s0, pw_s1, d_in[16], d_in[18], fsc3, flag);
  k_tne_cmix<<<NN/16, 256, 0, stream>>>(sm10, pwlt, fsc3, X9);

  for (int l=0; l<2; ++l){
    k_cmix_norm<<<NN/16, 256, 0, stream>>>(X9, pwlx2 + (size_t)l*3*16384, Y10);
    k_msg_sab<<<NN/NB, 128, 0, stream>>>(offsets, csrc,
        eabuf_msg + (size_t)l*NE*384, Y10, smb);
    k_cmix_fin<<<NN/16, 256, 0, stream>>>(smb, pwlt2 + (size_t)l*3*16384, X9, d_out,
        flag, (l==1)?1:0);
  }
}